// Round 1
// baseline (832.865 us; speedup 1.0000x reference)
//
#include <hip/hip_runtime.h>
#include <hip/hip_bf16.h>
#include <stdint.h>

// ---------------------------------------------------------------------------
// AbsBatchTopK: keep the top (top_k * 4096) elements of |x| over the whole
// 4096x16384 fp32 tensor, zero the rest. Exact tie handling (lowest index
// wins, matching jax.lax.top_k stability).
//
// Radix-select on abs bit patterns (monotonic for non-negative floats):
//   K1 init  : zero histogram + control block in ws
//   K2 hist  : 8192-bin LDS histogram of (bits >> 18)          [read 268MB]
//   K3 scan  : find threshold bin b and `need` within the bin
//   K4 pass2 : out = (bin>b) ? x : 0; compact bin-b candidates [read+write]
//   K5 select: exact K-th bit pattern + tie index threshold (1 block)
//   K6 fixup : scatter kept candidate values into out
// ---------------------------------------------------------------------------

#define NBINS 8192
#define BIN_SHIFT 18

// ws layout (uint words):
//   [0 .. NBINS-1]        histogram
//   [NBINS .. NBINS+15]   ctrl: 0=bin_b, 1=need, 2=cand_count, 3=t_bits, 4=idx_thr
//   byte offset 65536:    uint2 cand[cap]  (bits, idx)
//   after that:           float cval[cap]

__global__ void k_init(unsigned* ws) {
    int i = blockIdx.x * blockDim.x + threadIdx.x;
    if (i < NBINS + 16) ws[i] = 0u;
}

__global__ void k_hist(const float4* __restrict__ x4, long n4, long n,
                       unsigned* __restrict__ hist) {
    __shared__ unsigned lh[NBINS];
    for (int j = threadIdx.x; j < NBINS; j += blockDim.x) lh[j] = 0u;
    __syncthreads();
    long stride = (long)gridDim.x * blockDim.x;
    for (long i = blockIdx.x * (long)blockDim.x + threadIdx.x; i < n4; i += stride) {
        float4 v = x4[i];
        atomicAdd(&lh[(__float_as_uint(v.x) & 0x7fffffffu) >> BIN_SHIFT], 1u);
        atomicAdd(&lh[(__float_as_uint(v.y) & 0x7fffffffu) >> BIN_SHIFT], 1u);
        atomicAdd(&lh[(__float_as_uint(v.z) & 0x7fffffffu) >> BIN_SHIFT], 1u);
        atomicAdd(&lh[(__float_as_uint(v.w) & 0x7fffffffu) >> BIN_SHIFT], 1u);
    }
    // scalar tail (n not multiple of 4) — handled by block 0
    if (blockIdx.x == 0) {
        long base = n4 * 4;
        long rem = n - base;
        if ((long)threadIdx.x < rem) {
            const float* xs = (const float*)x4;
            unsigned bits = __float_as_uint(xs[base + threadIdx.x]) & 0x7fffffffu;
            atomicAdd(&lh[bits >> BIN_SHIFT], 1u);
        }
    }
    __syncthreads();
    for (int j = threadIdx.x; j < NBINS; j += blockDim.x) {
        unsigned c = lh[j];
        if (c) atomicAdd(&hist[j], c);
    }
}

// 1 block, 256 threads. Finds bin b s.t. cnt_above(b) < K <= cnt_above(b)+hist[b].
__global__ void k_scan(const unsigned* __restrict__ hist, unsigned* __restrict__ ctrl,
                       const int* __restrict__ topk) {
    __shared__ unsigned csum[256];
    int t = threadIdx.x;
    unsigned K = (unsigned)topk[0] * 4096u;  // bsz = 4096 (problem constant)
    int base = NBINS - 1 - t * 32;           // thread t covers bins [base-31, base], top-down
    unsigned s = 0;
    for (int j = 0; j < 32; ++j) s += hist[base - j];
    csum[t] = s;
    __syncthreads();
    // inclusive Hillis-Steele scan over csum (in t order == descending bins)
    for (int off = 1; off < 256; off <<= 1) {
        unsigned add = (t >= off) ? csum[t - off] : 0u;
        __syncthreads();
        csum[t] += add;
        __syncthreads();
    }
    unsigned before = csum[t] - s;  // count in all strictly-higher chunks
    if (before < K && before + s >= K) {
        unsigned cum = before;
        for (int j = 0; j < 32; ++j) {
            unsigned h = hist[base - j];
            if (cum + h >= K) {
                ctrl[0] = (unsigned)(base - j);  // bin b
                ctrl[1] = K - cum;               // need within bin b
                break;
            }
            cum += h;
        }
    }
}

__global__ void k_pass2(const float4* __restrict__ x4, float4* __restrict__ out4,
                        long n4, long n,
                        const unsigned* __restrict__ ctrl, unsigned* __restrict__ cnt,
                        uint2* __restrict__ cand, float* __restrict__ cval,
                        unsigned cap) {
    unsigned b = ctrl[0];
    long stride = (long)gridDim.x * blockDim.x;
    for (long i = blockIdx.x * (long)blockDim.x + threadIdx.x; i < n4; i += stride) {
        float4 v = x4[i];
        float4 o;
        #define PROC(comp, lane)                                                    \
        {                                                                           \
            unsigned bits = __float_as_uint(v.comp) & 0x7fffffffu;                  \
            unsigned bin = bits >> BIN_SHIFT;                                       \
            o.comp = (bin > b) ? v.comp : 0.0f;                                     \
            if (bin == b) {                                                         \
                unsigned p = atomicAdd(cnt, 1u);                                    \
                if (p < cap) {                                                      \
                    cand[p] = make_uint2(bits, (unsigned)(i * 4 + lane));           \
                    cval[p] = v.comp;                                               \
                }                                                                   \
            }                                                                       \
        }
        PROC(x, 0) PROC(y, 1) PROC(z, 2) PROC(w, 3)
        #undef PROC
        out4[i] = o;
    }
    // scalar tail
    if (blockIdx.x == 0) {
        long base = n4 * 4;
        long rem = n - base;
        if ((long)threadIdx.x < rem) {
            const float* xs = (const float*)x4;
            float* os = (float*)out4;
            long idx = base + threadIdx.x;
            float v = xs[idx];
            unsigned bits = __float_as_uint(v) & 0x7fffffffu;
            unsigned bin = bits >> BIN_SHIFT;
            os[idx] = (bin > b) ? v : 0.0f;
            if (bin == b) {
                unsigned p = atomicAdd(cnt, 1u);
                if (p < cap) {
                    cand[p] = make_uint2(bits, (unsigned)idx);
                    cval[p] = v;
                }
            }
        }
    }
}

// 1 block, 1024 threads. Exact need-th-largest bit pattern among candidates,
// then tie resolution by smallest index.
__global__ void k_select(unsigned* __restrict__ ctrl, const uint2* __restrict__ cand,
                         unsigned cap) {
    __shared__ unsigned red[1024];
    __shared__ unsigned tie_buf[1024];
    __shared__ unsigned tie_n;
    int t = threadIdx.x;
    unsigned m = ctrl[2] < cap ? ctrl[2] : cap;
    unsigned need = ctrl[1];
    unsigned b = ctrl[0];

    unsigned prefix = b << BIN_SHIFT;

    // count of candidates with bits >= test (block-wide)
    auto count_ge = [&](unsigned test) -> unsigned {
        unsigned c = 0;
        for (unsigned i = t; i < m; i += 1024) c += (cand[i].x >= test) ? 1u : 0u;
        red[t] = c;
        __syncthreads();
        for (int s2 = 512; s2 > 0; s2 >>= 1) {
            if (t < s2) red[t] += red[t + s2];
            __syncthreads();
        }
        unsigned r = red[0];
        __syncthreads();
        return r;
    };

    // radix binary search for the need-th largest bit pattern
    for (int bit = BIN_SHIFT - 1; bit >= 0; --bit) {
        unsigned test = prefix | (1u << bit);
        if (count_ge(test) >= need) prefix = test;
    }
    unsigned tb = prefix;
    unsigned cnt_gt = count_ge(tb + 1u);  // tb <= 0x7fffffff so no overflow past all
    unsigned tie_need = need - cnt_gt;    // >= 1 by construction

    if (t == 0) tie_n = 0u;
    __syncthreads();
    for (unsigned i = t; i < m; i += 1024) {
        if (cand[i].x == tb) {
            unsigned p = atomicAdd(&tie_n, 1u);
            if (p < 1024u) tie_buf[p] = cand[i].y;
        }
    }
    __syncthreads();
    if (t == 0) {
        unsigned I;
        if (tie_n <= tie_need) {
            I = 0xffffffffu;  // keep all tied
        } else {
            // tie_need-th smallest index among tied (indices unique)
            unsigned e = tie_n < 1024u ? tie_n : 1024u;
            unsigned prev = 0u;
            bool first = true;
            for (unsigned r = 0; r < tie_need; ++r) {
                unsigned mn = 0xffffffffu;
                for (unsigned j = 0; j < e; ++j) {
                    unsigned v2 = tie_buf[j];
                    if ((first || v2 > prev) && v2 < mn) mn = v2;
                }
                prev = mn;
                first = false;
            }
            I = prev;
        }
        ctrl[3] = tb;
        ctrl[4] = I;
    }
}

__global__ void k_fix(const unsigned* __restrict__ ctrl, const uint2* __restrict__ cand,
                      const float* __restrict__ cval, float* __restrict__ out,
                      unsigned cap) {
    unsigned m = ctrl[2] < cap ? ctrl[2] : cap;
    unsigned tb = ctrl[3];
    unsigned I = ctrl[4];
    unsigned stride = gridDim.x * blockDim.x;
    for (unsigned i = blockIdx.x * blockDim.x + threadIdx.x; i < m; i += stride) {
        uint2 c = cand[i];
        if (c.x > tb || (c.x == tb && c.y <= I)) out[c.y] = cval[i];
    }
}

extern "C" void kernel_launch(void* const* d_in, const int* in_sizes, int n_in,
                              void* d_out, int out_size, void* d_ws, size_t ws_size,
                              hipStream_t stream) {
    const float* x = (const float*)d_in[0];
    const int* topk = (const int*)d_in[1];
    float* out = (float*)d_out;
    long n = in_sizes[0];
    long n4 = n / 4;

    unsigned* ws = (unsigned*)d_ws;
    unsigned* hist = ws;
    unsigned* ctrl = ws + NBINS;
    uint2* cand = (uint2*)((char*)d_ws + 65536);
    size_t avail = ws_size > 65536 ? ws_size - 65536 : 0;
    size_t cap_sz = avail / 12;  // 8B cand + 4B cval per entry
    unsigned cap = (unsigned)(cap_sz < (size_t)(1u << 22) ? cap_sz : (size_t)(1u << 22));
    float* cval = (float*)(cand + cap);

    k_init<<<(NBINS + 16 + 255) / 256, 256, 0, stream>>>(ws);
    k_hist<<<2048, 256, 0, stream>>>((const float4*)x, n4, n, hist);
    k_scan<<<1, 256, 0, stream>>>(hist, ctrl, topk);
    k_pass2<<<2048, 256, 0, stream>>>((const float4*)x, (float4*)out, n4, n,
                                      ctrl, ctrl + 2, cand, cval, cap);
    k_select<<<1, 1024, 0, stream>>>(ctrl, cand, cap);
    k_fix<<<256, 256, 0, stream>>>(ctrl, cand, cval, out, cap);
}

// Round 2
// 764.801 us; speedup vs baseline: 1.0890x; 1.0890x over previous
//
#include <hip/hip_runtime.h>
#include <hip/hip_bf16.h>
#include <stdint.h>

// ---------------------------------------------------------------------------
// AbsBatchTopK: keep the top (top_k * 4096) elements of |x| over the whole
// 4096x16384 fp32 tensor, zero the rest. Exact (lowest index wins ties).
//
// Radix-select on abs bit patterns (monotonic for non-negative floats):
//   K1 init  : zero histogram + control block in ws
//   K2 hist  : 8192-bin LDS histogram of (bits >> 18)          [read 268MB]
//   K3 scan  : find threshold bin b and `need` within the bin
//   K4 pass2 : out = (bin>b) ? x : 0; compact bin-b candidates [read+write]
//   K5 select: exact K-th bit pattern + tie index threshold (1 block, LDS)
//   K6 fixup : scatter kept candidate values into out
// ---------------------------------------------------------------------------

#define NBINS 8192
#define BIN_SHIFT 18
#define SEL_LDS 32768

// ws layout (uint words):
//   [0 .. NBINS-1]        histogram
//   [NBINS .. NBINS+15]   ctrl: 0=bin_b, 1=need, 2=cand_count, 3=t_bits, 4=idx_thr
//   byte offset 65536:    uint2 cand[cap]  (bits, idx)
//   after that:           float cval[cap]

__global__ void k_init(unsigned* ws) {
    int i = blockIdx.x * blockDim.x + threadIdx.x;
    if (i < NBINS + 16) ws[i] = 0u;
}

__global__ __launch_bounds__(256) void k_hist(const float4* __restrict__ x4,
                                              long n4, long n,
                                              unsigned* __restrict__ hist) {
    __shared__ unsigned lh[NBINS];
    for (int j = threadIdx.x; j < NBINS; j += 256) lh[j] = 0u;
    __syncthreads();
    long stride = (long)gridDim.x * 256;
    long i = (long)blockIdx.x * 256 + threadIdx.x;
    for (; i + 3 * stride < n4; i += 4 * stride) {
        float4 v0 = x4[i];
        float4 v1 = x4[i + stride];
        float4 v2 = x4[i + 2 * stride];
        float4 v3 = x4[i + 3 * stride];
        #define H(v)                                                              \
            atomicAdd(&lh[(__float_as_uint(v.x) & 0x7fffffffu) >> BIN_SHIFT], 1u);\
            atomicAdd(&lh[(__float_as_uint(v.y) & 0x7fffffffu) >> BIN_SHIFT], 1u);\
            atomicAdd(&lh[(__float_as_uint(v.z) & 0x7fffffffu) >> BIN_SHIFT], 1u);\
            atomicAdd(&lh[(__float_as_uint(v.w) & 0x7fffffffu) >> BIN_SHIFT], 1u);
        H(v0) H(v1) H(v2) H(v3)
        #undef H
    }
    for (; i < n4; i += stride) {
        float4 v = x4[i];
        atomicAdd(&lh[(__float_as_uint(v.x) & 0x7fffffffu) >> BIN_SHIFT], 1u);
        atomicAdd(&lh[(__float_as_uint(v.y) & 0x7fffffffu) >> BIN_SHIFT], 1u);
        atomicAdd(&lh[(__float_as_uint(v.z) & 0x7fffffffu) >> BIN_SHIFT], 1u);
        atomicAdd(&lh[(__float_as_uint(v.w) & 0x7fffffffu) >> BIN_SHIFT], 1u);
    }
    if (blockIdx.x == 0) {
        long base = n4 * 4;
        long rem = n - base;
        if ((long)threadIdx.x < rem) {
            const float* xs = (const float*)x4;
            unsigned bits = __float_as_uint(xs[base + threadIdx.x]) & 0x7fffffffu;
            atomicAdd(&lh[bits >> BIN_SHIFT], 1u);
        }
    }
    __syncthreads();
    for (int j = threadIdx.x; j < NBINS; j += 256) {
        unsigned c = lh[j];
        if (c) atomicAdd(&hist[j], c);
    }
}

// 1 block, 256 threads. Finds bin b s.t. cnt_above(b) < K <= cnt_above(b)+hist[b].
__global__ void k_scan(const unsigned* __restrict__ hist, unsigned* __restrict__ ctrl,
                       const int* __restrict__ topk) {
    __shared__ unsigned csum[256];
    int t = threadIdx.x;
    unsigned K = (unsigned)topk[0] * 4096u;  // bsz = 4096 (problem constant)
    int base = NBINS - 1 - t * 32;           // thread t covers bins [base-31, base]
    unsigned s = 0;
    for (int j = 0; j < 32; ++j) s += hist[base - j];
    csum[t] = s;
    __syncthreads();
    for (int off = 1; off < 256; off <<= 1) {
        unsigned add = (t >= off) ? csum[t - off] : 0u;
        __syncthreads();
        csum[t] += add;
        __syncthreads();
    }
    unsigned before = csum[t] - s;
    if (before < K && before + s >= K) {
        unsigned cum = before;
        for (int j = 0; j < 32; ++j) {
            unsigned h = hist[base - j];
            if (cum + h >= K) {
                ctrl[0] = (unsigned)(base - j);  // bin b
                ctrl[1] = K - cum;               // need within bin b
                break;
            }
            cum += h;
        }
    }
}

// branchless per-float4 processing: output select + 4-bit candidate mask
__device__ __forceinline__ unsigned proc4(float4 v, float4& o, unsigned b) {
    unsigned bx = __float_as_uint(v.x) & 0x7fffffffu;
    unsigned by = __float_as_uint(v.y) & 0x7fffffffu;
    unsigned bz = __float_as_uint(v.z) & 0x7fffffffu;
    unsigned bw = __float_as_uint(v.w) & 0x7fffffffu;
    o.x = ((bx >> BIN_SHIFT) > b) ? v.x : 0.0f;
    o.y = ((by >> BIN_SHIFT) > b) ? v.y : 0.0f;
    o.z = ((bz >> BIN_SHIFT) > b) ? v.z : 0.0f;
    o.w = ((bw >> BIN_SHIFT) > b) ? v.w : 0.0f;
    unsigned m = 0;
    m |= ((bx >> BIN_SHIFT) == b) ? 1u : 0u;
    m |= ((by >> BIN_SHIFT) == b) ? 2u : 0u;
    m |= ((bz >> BIN_SHIFT) == b) ? 4u : 0u;
    m |= ((bw >> BIN_SHIFT) == b) ? 8u : 0u;
    return m;
}

__device__ __forceinline__ void emit4(unsigned msk, float4 v, long i4,
                                      unsigned* cnt, uint2* cand, float* cval,
                                      unsigned cap) {
    while (msk) {
        int j = __ffs(msk) - 1;
        msk &= msk - 1;
        float val = (j == 0) ? v.x : (j == 1) ? v.y : (j == 2) ? v.z : v.w;
        unsigned bits = __float_as_uint(val) & 0x7fffffffu;
        unsigned p = atomicAdd(cnt, 1u);
        if (p < cap) {
            cand[p] = make_uint2(bits, (unsigned)(i4 * 4 + j));
            cval[p] = val;
        }
    }
}

__global__ __launch_bounds__(256) void k_pass2(const float4* __restrict__ x4,
                                               float4* __restrict__ out4,
                                               long n4, long n,
                                               const unsigned* __restrict__ ctrl,
                                               unsigned* __restrict__ cnt,
                                               uint2* __restrict__ cand,
                                               float* __restrict__ cval,
                                               unsigned cap) {
    unsigned b = ctrl[0];
    long stride = (long)gridDim.x * 256;
    long i = (long)blockIdx.x * 256 + threadIdx.x;
    for (; i + 3 * stride < n4; i += 4 * stride) {
        float4 v0 = x4[i];
        float4 v1 = x4[i + stride];
        float4 v2 = x4[i + 2 * stride];
        float4 v3 = x4[i + 3 * stride];
        float4 o0, o1, o2, o3;
        unsigned m0 = proc4(v0, o0, b);
        unsigned m1 = proc4(v1, o1, b);
        unsigned m2 = proc4(v2, o2, b);
        unsigned m3 = proc4(v3, o3, b);
        out4[i] = o0;
        out4[i + stride] = o1;
        out4[i + 2 * stride] = o2;
        out4[i + 3 * stride] = o3;
        if (__any((int)(m0 | m1 | m2 | m3))) {  // rare: ~1 in 600 groups
            emit4(m0, v0, i, cnt, cand, cval, cap);
            emit4(m1, v1, i + stride, cnt, cand, cval, cap);
            emit4(m2, v2, i + 2 * stride, cnt, cand, cval, cap);
            emit4(m3, v3, i + 3 * stride, cnt, cand, cval, cap);
        }
    }
    for (; i < n4; i += stride) {
        float4 v = x4[i];
        float4 o;
        unsigned m = proc4(v, o, b);
        out4[i] = o;
        if (__any((int)m)) emit4(m, v, i, cnt, cand, cval, cap);
    }
    if (blockIdx.x == 0) {
        long base = n4 * 4;
        long rem = n - base;
        if ((long)threadIdx.x < rem) {
            const float* xs = (const float*)x4;
            float* os = (float*)out4;
            long idx = base + threadIdx.x;
            float v = xs[idx];
            unsigned bits = __float_as_uint(v) & 0x7fffffffu;
            unsigned bin = bits >> BIN_SHIFT;
            os[idx] = (bin > b) ? v : 0.0f;
            if (bin == b) {
                unsigned p = atomicAdd(cnt, 1u);
                if (p < cap) {
                    cand[p] = make_uint2(bits, (unsigned)idx);
                    cval[p] = v;
                }
            }
        }
    }
}

// 1 block, 1024 threads. Exact need-th-largest bit pattern among candidates,
// then tie resolution by smallest index. Candidate bits staged in LDS.
__global__ __launch_bounds__(1024) void k_select(unsigned* __restrict__ ctrl,
                                                 const uint2* __restrict__ cand,
                                                 unsigned cap) {
    __shared__ unsigned sbits[SEL_LDS];
    __shared__ unsigned wsum[16];
    __shared__ unsigned tie_buf[1024];
    __shared__ unsigned tie_n;
    int t = threadIdx.x;
    int lane = t & 63, wid = t >> 6;
    unsigned m = ctrl[2] < cap ? ctrl[2] : cap;
    unsigned need = ctrl[1];
    unsigned b = ctrl[0];
    unsigned mL = m < (unsigned)SEL_LDS ? m : (unsigned)SEL_LDS;

    for (unsigned i = t; i < mL; i += 1024) sbits[i] = cand[i].x;
    __syncthreads();

    auto count_ge = [&](unsigned test) -> unsigned {
        unsigned c = 0;
        for (unsigned i = t; i < mL; i += 1024) c += (sbits[i] >= test) ? 1u : 0u;
        for (unsigned i = SEL_LDS + t; i < m; i += 1024) c += (cand[i].x >= test) ? 1u : 0u;
        for (int off = 32; off > 0; off >>= 1) c += __shfl_down(c, off, 64);
        if (lane == 0) wsum[wid] = c;
        __syncthreads();
        unsigned r = 0;
        #pragma unroll
        for (int j = 0; j < 16; ++j) r += wsum[j];
        __syncthreads();
        return r;
    };

    unsigned prefix = b << BIN_SHIFT;
    for (int bit = BIN_SHIFT - 1; bit >= 0; --bit) {
        unsigned test = prefix | (1u << bit);
        if (count_ge(test) >= need) prefix = test;
    }
    unsigned tb = prefix;
    unsigned cnt_gt = count_ge(tb + 1u);
    unsigned tie_need = need - cnt_gt;  // >= 1 by construction

    if (t == 0) tie_n = 0u;
    __syncthreads();
    for (unsigned i = t; i < m; i += 1024) {
        unsigned bits = (i < mL) ? sbits[i] : cand[i].x;
        if (bits == tb) {
            unsigned p = atomicAdd(&tie_n, 1u);
            if (p < 1024u) tie_buf[p] = cand[i].y;
        }
    }
    __syncthreads();
    if (t == 0) {
        unsigned I;
        if (tie_n <= tie_need) {
            I = 0xffffffffu;  // keep all tied
        } else {
            unsigned e = tie_n < 1024u ? tie_n : 1024u;
            unsigned prev = 0u;
            bool first = true;
            for (unsigned r = 0; r < tie_need; ++r) {
                unsigned mn = 0xffffffffu;
                for (unsigned j = 0; j < e; ++j) {
                    unsigned v2 = tie_buf[j];
                    if ((first || v2 > prev) && v2 < mn) mn = v2;
                }
                prev = mn;
                first = false;
            }
            I = prev;
        }
        ctrl[3] = tb;
        ctrl[4] = I;
    }
}

__global__ void k_fix(const unsigned* __restrict__ ctrl, const uint2* __restrict__ cand,
                      const float* __restrict__ cval, float* __restrict__ out,
                      unsigned cap) {
    unsigned m = ctrl[2] < cap ? ctrl[2] : cap;
    unsigned tb = ctrl[3];
    unsigned I = ctrl[4];
    unsigned stride = gridDim.x * blockDim.x;
    for (unsigned i = blockIdx.x * blockDim.x + threadIdx.x; i < m; i += stride) {
        uint2 c = cand[i];
        if (c.x > tb || (c.x == tb && c.y <= I)) out[c.y] = cval[i];
    }
}

extern "C" void kernel_launch(void* const* d_in, const int* in_sizes, int n_in,
                              void* d_out, int out_size, void* d_ws, size_t ws_size,
                              hipStream_t stream) {
    const float* x = (const float*)d_in[0];
    const int* topk = (const int*)d_in[1];
    float* out = (float*)d_out;
    long n = in_sizes[0];
    long n4 = n / 4;

    unsigned* ws = (unsigned*)d_ws;
    unsigned* hist = ws;
    unsigned* ctrl = ws + NBINS;
    uint2* cand = (uint2*)((char*)d_ws + 65536);
    size_t avail = ws_size > 65536 ? ws_size - 65536 : 0;
    size_t cap_sz = avail / 12;  // 8B cand + 4B cval per entry
    unsigned cap = (unsigned)(cap_sz < (size_t)(1u << 22) ? cap_sz : (size_t)(1u << 22));
    float* cval = (float*)(cand + cap);

    k_init<<<(NBINS + 16 + 255) / 256, 256, 0, stream>>>(ws);
    k_hist<<<2048, 256, 0, stream>>>((const float4*)x, n4, n, hist);
    k_scan<<<1, 256, 0, stream>>>(hist, ctrl, topk);
    k_pass2<<<2048, 256, 0, stream>>>((const float4*)x, (float4*)out, n4, n,
                                      ctrl, ctrl + 2, cand, cval, cap);
    k_select<<<1, 1024, 0, stream>>>(ctrl, cand, cap);
    k_fix<<<256, 256, 0, stream>>>(ctrl, cand, cval, out, cap);
}

// Round 4
// 523.910 us; speedup vs baseline: 1.5897x; 1.4598x over previous
//
#include <hip/hip_runtime.h>
#include <hip/hip_bf16.h>
#include <stdint.h>

// ---------------------------------------------------------------------------
// AbsBatchTopK: keep the top (top_k * 4096) elements of |x| over the whole
// 4096x16384 fp32 tensor, zero the rest. Exact (lowest index wins ties).
//
// Radix-select on abs bit patterns (monotonic for non-negative floats):
//   K1 init  : zero histogram + control block in ws
//   K2 hist  : 8192-bin LDS histogram of (bits >> 18)          [read 268MB]
//   K3 scan  : find threshold bin b and `need` within the bin
//   K4 pass2 : out = (bin>b) ? x : 0 (nt stores); bin-b candidates staged in
//              per-block LDS, ONE global atomic per block      [read+write]
//   K5 select: exact K-th bit pattern + tie index threshold (1 block, LDS)
//   K6 fixup : scatter kept candidate values into out
// ---------------------------------------------------------------------------

#define NBINS 8192
#define BIN_SHIFT 18
#define SEL_LDS 32768
#define P2_BUF 2048

typedef float nfloat4 __attribute__((ext_vector_type(4)));

__device__ __forceinline__ void nt_store4(float4 v, float4* p) {
    nfloat4 nv;
    nv.x = v.x; nv.y = v.y; nv.z = v.z; nv.w = v.w;
    __builtin_nontemporal_store(nv, reinterpret_cast<nfloat4*>(p));
}

// ws layout (uint words):
//   [0 .. NBINS-1]        histogram
//   [NBINS .. NBINS+15]   ctrl: 0=bin_b, 1=need, 2=cand_count, 3=t_bits, 4=idx_thr
//   byte offset 65536:    uint2 cand[cap]  (bits, idx)
//   after that:           float cval[cap]

__global__ void k_init(unsigned* ws) {
    int i = blockIdx.x * blockDim.x + threadIdx.x;
    if (i < NBINS + 16) ws[i] = 0u;
}

__global__ __launch_bounds__(256) void k_hist(const float4* __restrict__ x4,
                                              long n4, long n,
                                              unsigned* __restrict__ hist) {
    __shared__ unsigned lh[NBINS];
    for (int j = threadIdx.x; j < NBINS; j += 256) lh[j] = 0u;
    __syncthreads();
    long stride = (long)gridDim.x * 256;
    long i = (long)blockIdx.x * 256 + threadIdx.x;
    for (; i + 3 * stride < n4; i += 4 * stride) {
        float4 v0 = x4[i];
        float4 v1 = x4[i + stride];
        float4 v2 = x4[i + 2 * stride];
        float4 v3 = x4[i + 3 * stride];
        #define H(v)                                                              \
            atomicAdd(&lh[(__float_as_uint(v.x) & 0x7fffffffu) >> BIN_SHIFT], 1u);\
            atomicAdd(&lh[(__float_as_uint(v.y) & 0x7fffffffu) >> BIN_SHIFT], 1u);\
            atomicAdd(&lh[(__float_as_uint(v.z) & 0x7fffffffu) >> BIN_SHIFT], 1u);\
            atomicAdd(&lh[(__float_as_uint(v.w) & 0x7fffffffu) >> BIN_SHIFT], 1u);
        H(v0) H(v1) H(v2) H(v3)
        #undef H
    }
    for (; i < n4; i += stride) {
        float4 v = x4[i];
        atomicAdd(&lh[(__float_as_uint(v.x) & 0x7fffffffu) >> BIN_SHIFT], 1u);
        atomicAdd(&lh[(__float_as_uint(v.y) & 0x7fffffffu) >> BIN_SHIFT], 1u);
        atomicAdd(&lh[(__float_as_uint(v.z) & 0x7fffffffu) >> BIN_SHIFT], 1u);
        atomicAdd(&lh[(__float_as_uint(v.w) & 0x7fffffffu) >> BIN_SHIFT], 1u);
    }
    if (blockIdx.x == 0) {
        long base = n4 * 4;
        long rem = n - base;
        if ((long)threadIdx.x < rem) {
            const float* xs = (const float*)x4;
            unsigned bits = __float_as_uint(xs[base + threadIdx.x]) & 0x7fffffffu;
            atomicAdd(&lh[bits >> BIN_SHIFT], 1u);
        }
    }
    __syncthreads();
    for (int j = threadIdx.x; j < NBINS; j += 256) {
        unsigned c = lh[j];
        if (c) atomicAdd(&hist[j], c);
    }
}

// 1 block, 256 threads. Finds bin b s.t. cnt_above(b) < K <= cnt_above(b)+hist[b].
__global__ void k_scan(const unsigned* __restrict__ hist, unsigned* __restrict__ ctrl,
                       const int* __restrict__ topk) {
    __shared__ unsigned csum[256];
    int t = threadIdx.x;
    unsigned K = (unsigned)topk[0] * 4096u;  // bsz = 4096 (problem constant)
    int base = NBINS - 1 - t * 32;           // thread t covers bins [base-31, base]
    unsigned s = 0;
    for (int j = 0; j < 32; ++j) s += hist[base - j];
    csum[t] = s;
    __syncthreads();
    for (int off = 1; off < 256; off <<= 1) {
        unsigned add = (t >= off) ? csum[t - off] : 0u;
        __syncthreads();
        csum[t] += add;
        __syncthreads();
    }
    unsigned before = csum[t] - s;
    if (before < K && before + s >= K) {
        unsigned cum = before;
        for (int j = 0; j < 32; ++j) {
            unsigned h = hist[base - j];
            if (cum + h >= K) {
                ctrl[0] = (unsigned)(base - j);  // bin b
                ctrl[1] = K - cum;               // need within bin b
                break;
            }
            cum += h;
        }
    }
}

// branchless per-float4 processing: output select + 4-bit candidate mask
__device__ __forceinline__ unsigned proc4(float4 v, float4& o, unsigned b) {
    unsigned bx = __float_as_uint(v.x) & 0x7fffffffu;
    unsigned by = __float_as_uint(v.y) & 0x7fffffffu;
    unsigned bz = __float_as_uint(v.z) & 0x7fffffffu;
    unsigned bw = __float_as_uint(v.w) & 0x7fffffffu;
    o.x = ((bx >> BIN_SHIFT) > b) ? v.x : 0.0f;
    o.y = ((by >> BIN_SHIFT) > b) ? v.y : 0.0f;
    o.z = ((bz >> BIN_SHIFT) > b) ? v.z : 0.0f;
    o.w = ((bw >> BIN_SHIFT) > b) ? v.w : 0.0f;
    unsigned m = 0;
    m |= ((bx >> BIN_SHIFT) == b) ? 1u : 0u;
    m |= ((by >> BIN_SHIFT) == b) ? 2u : 0u;
    m |= ((bz >> BIN_SHIFT) == b) ? 4u : 0u;
    m |= ((bw >> BIN_SHIFT) == b) ? 8u : 0u;
    return m;
}

struct P2Shared {
    unsigned l_cnt;
    unsigned l_base;
    unsigned l_bits[P2_BUF];
    unsigned l_idx[P2_BUF];
    float l_val[P2_BUF];
};

// append candidates from mask to the block-local LDS buffer (global fallback
// only on LDS overflow, which is astronomically rare for sane inputs)
__device__ __forceinline__ void emit4_lds(unsigned msk, float4 v, long i4,
                                          P2Shared& sh, unsigned* cnt,
                                          uint2* cand, float* cval, unsigned cap) {
    while (msk) {
        int j = __ffs(msk) - 1;
        msk &= msk - 1;
        float val = (j == 0) ? v.x : (j == 1) ? v.y : (j == 2) ? v.z : v.w;
        unsigned bits = __float_as_uint(val) & 0x7fffffffu;
        unsigned idx = (unsigned)(i4 * 4 + j);
        unsigned p = atomicAdd(&sh.l_cnt, 1u);
        if (p < P2_BUF) {
            sh.l_bits[p] = bits;
            sh.l_idx[p] = idx;
            sh.l_val[p] = val;
        } else {  // overflow: direct global append (slot unique vs block reservations)
            unsigned g = atomicAdd(cnt, 1u);
            if (g < cap) {
                cand[g] = make_uint2(bits, idx);
                cval[g] = val;
            }
        }
    }
}

__global__ __launch_bounds__(256) void k_pass2(const float4* __restrict__ x4,
                                               float4* __restrict__ out4,
                                               long n4, long n,
                                               const unsigned* __restrict__ ctrl,
                                               unsigned* __restrict__ cnt,
                                               uint2* __restrict__ cand,
                                               float* __restrict__ cval,
                                               unsigned cap) {
    __shared__ P2Shared sh;
    if (threadIdx.x == 0) sh.l_cnt = 0u;
    __syncthreads();
    unsigned b = ctrl[0];
    long stride = (long)gridDim.x * 256;
    long i = (long)blockIdx.x * 256 + threadIdx.x;
    for (; i + 3 * stride < n4; i += 4 * stride) {
        float4 v0 = x4[i];
        float4 v1 = x4[i + stride];
        float4 v2 = x4[i + 2 * stride];
        float4 v3 = x4[i + 3 * stride];
        float4 o0, o1, o2, o3;
        unsigned m0 = proc4(v0, o0, b);
        unsigned m1 = proc4(v1, o1, b);
        unsigned m2 = proc4(v2, o2, b);
        unsigned m3 = proc4(v3, o3, b);
        nt_store4(o0, &out4[i]);
        nt_store4(o1, &out4[i + stride]);
        nt_store4(o2, &out4[i + 2 * stride]);
        nt_store4(o3, &out4[i + 3 * stride]);
        if (__any((int)(m0 | m1 | m2 | m3))) {  // rare: ~1 in 3 wave-groups
            emit4_lds(m0, v0, i, sh, cnt, cand, cval, cap);
            emit4_lds(m1, v1, i + stride, sh, cnt, cand, cval, cap);
            emit4_lds(m2, v2, i + 2 * stride, sh, cnt, cand, cval, cap);
            emit4_lds(m3, v3, i + 3 * stride, sh, cnt, cand, cval, cap);
        }
    }
    for (; i < n4; i += stride) {
        float4 v = x4[i];
        float4 o;
        unsigned m = proc4(v, o, b);
        nt_store4(o, &out4[i]);
        if (__any((int)m)) emit4_lds(m, v, i, sh, cnt, cand, cval, cap);
    }
    if (blockIdx.x == 0) {
        long base = n4 * 4;
        long rem = n - base;
        if ((long)threadIdx.x < rem) {
            const float* xs = (const float*)x4;
            float* os = (float*)out4;
            long idx = base + threadIdx.x;
            float v = xs[idx];
            unsigned bits = __float_as_uint(v) & 0x7fffffffu;
            unsigned bin = bits >> BIN_SHIFT;
            os[idx] = (bin > b) ? v : 0.0f;
            if (bin == b) {
                unsigned p = atomicAdd(&sh.l_cnt, 1u);
                if (p < P2_BUF) {
                    sh.l_bits[p] = bits; sh.l_idx[p] = idx; sh.l_val[p] = v;
                } else {
                    unsigned g = atomicAdd(cnt, 1u);
                    if (g < cap) { cand[g] = make_uint2(bits, (unsigned)idx); cval[g] = v; }
                }
            }
        }
    }
    // block-end: one global reservation, coalesced LDS -> global copy
    __syncthreads();
    unsigned c = sh.l_cnt < (unsigned)P2_BUF ? sh.l_cnt : (unsigned)P2_BUF;
    if (threadIdx.x == 0) sh.l_base = c ? atomicAdd(cnt, c) : 0u;
    __syncthreads();
    unsigned base2 = sh.l_base;
    for (unsigned j = threadIdx.x; j < c; j += 256) {
        unsigned p = base2 + j;
        if (p < cap) {
            cand[p] = make_uint2(sh.l_bits[j], sh.l_idx[j]);
            cval[p] = sh.l_val[j];
        }
    }
}

// 1 block, 1024 threads. Exact need-th-largest bit pattern among candidates,
// then tie resolution by smallest index. Candidate bits staged in LDS.
__global__ __launch_bounds__(1024) void k_select(unsigned* __restrict__ ctrl,
                                                 const uint2* __restrict__ cand,
                                                 unsigned cap) {
    __shared__ unsigned sbits[SEL_LDS];
    __shared__ unsigned wsum[16];
    __shared__ unsigned tie_buf[1024];
    __shared__ unsigned tie_n;
    int t = threadIdx.x;
    int lane = t & 63, wid = t >> 6;
    unsigned m = ctrl[2] < cap ? ctrl[2] : cap;
    unsigned need = ctrl[1];
    unsigned b = ctrl[0];
    unsigned mL = m < (unsigned)SEL_LDS ? m : (unsigned)SEL_LDS;

    for (unsigned i = t; i < mL; i += 1024) sbits[i] = cand[i].x;
    __syncthreads();

    auto count_ge = [&](unsigned test) -> unsigned {
        unsigned c = 0;
        for (unsigned i = t; i < mL; i += 1024) c += (sbits[i] >= test) ? 1u : 0u;
        for (unsigned i = SEL_LDS + t; i < m; i += 1024) c += (cand[i].x >= test) ? 1u : 0u;
        for (int off = 32; off > 0; off >>= 1) c += __shfl_down(c, off, 64);
        if (lane == 0) wsum[wid] = c;
        __syncthreads();
        unsigned r = 0;
        #pragma unroll
        for (int j = 0; j < 16; ++j) r += wsum[j];
        __syncthreads();
        return r;
    };

    unsigned prefix = b << BIN_SHIFT;
    for (int bit = BIN_SHIFT - 1; bit >= 0; --bit) {
        unsigned test = prefix | (1u << bit);
        if (count_ge(test) >= need) prefix = test;
    }
    unsigned tb = prefix;
    unsigned cnt_gt = count_ge(tb + 1u);
    unsigned tie_need = need - cnt_gt;  // >= 1 by construction

    if (t == 0) tie_n = 0u;
    __syncthreads();
    for (unsigned i = t; i < m; i += 1024) {
        unsigned bits = (i < mL) ? sbits[i] : cand[i].x;
        if (bits == tb) {
            unsigned p = atomicAdd(&tie_n, 1u);
            if (p < 1024u) tie_buf[p] = cand[i].y;
        }
    }
    __syncthreads();
    if (t == 0) {
        unsigned I;
        if (tie_n <= tie_need) {
            I = 0xffffffffu;  // keep all tied
        } else {
            unsigned e = tie_n < 1024u ? tie_n : 1024u;
            unsigned prev = 0u;
            bool first = true;
            for (unsigned r = 0; r < tie_need; ++r) {
                unsigned mn = 0xffffffffu;
                for (unsigned j = 0; j < e; ++j) {
                    unsigned v2 = tie_buf[j];
                    if ((first || v2 > prev) && v2 < mn) mn = v2;
                }
                prev = mn;
                first = false;
            }
            I = prev;
        }
        ctrl[3] = tb;
        ctrl[4] = I;
    }
}

__global__ void k_fix(const unsigned* __restrict__ ctrl, const uint2* __restrict__ cand,
                      const float* __restrict__ cval, float* __restrict__ out,
                      unsigned cap) {
    unsigned m = ctrl[2] < cap ? ctrl[2] : cap;
    unsigned tb = ctrl[3];
    unsigned I = ctrl[4];
    unsigned stride = gridDim.x * blockDim.x;
    for (unsigned i = blockIdx.x * blockDim.x + threadIdx.x; i < m; i += stride) {
        uint2 c = cand[i];
        if (c.x > tb || (c.x == tb && c.y <= I)) out[c.y] = cval[i];
    }
}

extern "C" void kernel_launch(void* const* d_in, const int* in_sizes, int n_in,
                              void* d_out, int out_size, void* d_ws, size_t ws_size,
                              hipStream_t stream) {
    const float* x = (const float*)d_in[0];
    const int* topk = (const int*)d_in[1];
    float* out = (float*)d_out;
    long n = in_sizes[0];
    long n4 = n / 4;

    unsigned* ws = (unsigned*)d_ws;
    unsigned* hist = ws;
    unsigned* ctrl = ws + NBINS;
    uint2* cand = (uint2*)((char*)d_ws + 65536);
    size_t avail = ws_size > 65536 ? ws_size - 65536 : 0;
    size_t cap_sz = avail / 12;  // 8B cand + 4B cval per entry
    unsigned cap = (unsigned)(cap_sz < (size_t)(1u << 22) ? cap_sz : (size_t)(1u << 22));
    float* cval = (float*)(cand + cap);

    k_init<<<(NBINS + 16 + 255) / 256, 256, 0, stream>>>(ws);
    k_hist<<<2048, 256, 0, stream>>>((const float4*)x, n4, n, hist);
    k_scan<<<1, 256, 0, stream>>>(hist, ctrl, topk);
    k_pass2<<<4096, 256, 0, stream>>>((const float4*)x, (float4*)out, n4, n,
                                      ctrl, ctrl + 2, cand, cval, cap);
    k_select<<<1, 1024, 0, stream>>>(ctrl, cand, cap);
    k_fix<<<256, 256, 0, stream>>>(ctrl, cand, cval, out, cap);
}